// Round 7
// baseline (271.238 us; speedup 1.0000x reference)
//
#include <hip/hip_runtime.h>
#include <math.h>

#define SLEN 8000
#define NBATCH 512
#define DDIM 256

// ---- fused conv+pointwise config ----
#define RAD 160
#define TAPS 321                 // truncated Gaussian: tail mass ~1e-7
#define CHUNK 2048
#define CBLK 128                 // 2 waves
#define TPO 16                   // outputs per thread
#define HALO_L 176               // 16 extra left so v_s[i0-1] is computable
#define WIN 2400                 // 176 + 2048 + 160 + 16 slack (exactly fits prefetch)
#define LDSZ 2700                // phi(2399)=2698; phi(x)=x+(x>>3), stride-18 lanes: 2-way=free

// output element offsets (flat concat in reference return order)
#define O0  0            // dv_out sliced  512*7700
#define O1  3942400      // dv_t           512*8000
#define O2  8038400      // dv2_t          512*8000
#define O3  12134400     // a              512
#define O4  12134912     // k*1000         512
#define O5  12135424     // epsilon        512
#define O6  12135936     // gamma          512
#define O7  12136448     // t_             512*8000
#define O8  16232448     // dv_l           512*8001
#define O9  20328960     // dv_r           512*8001
#define O10 24425472     // t_out          512*8000

#define WS_WTAB 2048     // weight table lives at wsp + 2048 (321 floats)

// raw clang vectors: __builtin_nontemporal_store rejects HIP_vector_type
typedef float f4a __attribute__((vector_size(16)));               // 16B-aligned
typedef float f4u __attribute__((vector_size(16), aligned(4)));   // 4B-aligned

__device__ __forceinline__ void nt_store4(float* p, float a, float b, float c, float d) {
    f4a v = {a, b, c, d};
    __builtin_nontemporal_store(v, (f4a*)p);
}
__device__ __forceinline__ void nt_store4u(float* p, float a, float b, float c, float d) {
    f4u v = {a, b, c, d};
    __builtin_nontemporal_store(v, (f4u*)p);
}

// ---------------- weight table: double-precision Gaussian taps ---------------
__global__ __launch_bounds__(384) void pc_wtab_kernel(float* __restrict__ wtab) {
    const int j = threadIdx.x;
    if (j < TAPS) {
        const double d = (double)(j - RAD);
        // norm = sum_{-3500..3500} exp(-d^2/1800) = sigma*sqrt(2pi) to ~1e-16
        wtab[j] = (float)(exp(-d * d / 1800.0) * (1.0 / 75.1988482389300059));
    }
}

// ---------------- params: one wave per row, shfl butterfly reduction ---------
__global__ __launch_bounds__(64) void pc_params_kernel(
    const float* __restrict__ b,
    const float* __restrict__ kw, const float* __restrict__ kb,
    const float* __restrict__ aw, const float* __restrict__ ab,
    const float* __restrict__ ew, const float* __restrict__ eb,
    const float* __restrict__ gw, const float* __restrict__ gb,
    float* __restrict__ out3, float* __restrict__ out4,
    float* __restrict__ out5, float* __restrict__ out6,
    float* __restrict__ wsp)
{
    const int row = blockIdx.x;
    const int l = threadIdx.x;
    const float4 bb = *(const float4*)(b + (long)row * DDIM + 4 * l);
    const float4 k4 = *(const float4*)(kw + 4 * l);
    const float4 a4 = *(const float4*)(aw + 4 * l);
    const float4 e4 = *(const float4*)(ew + 4 * l);
    const float4 g4 = *(const float4*)(gw + 4 * l);
    float sk = bb.x * k4.x + bb.y * k4.y + bb.z * k4.z + bb.w * k4.w;
    float sa = bb.x * a4.x + bb.y * a4.y + bb.z * a4.z + bb.w * a4.w;
    float se = bb.x * e4.x + bb.y * e4.y + bb.z * e4.z + bb.w * e4.w;
    float sg = bb.x * g4.x + bb.y * g4.y + bb.z * g4.z + bb.w * g4.w;
#pragma unroll
    for (int m = 1; m < 64; m <<= 1) {
        sk += __shfl_xor(sk, m, 64);
        sa += __shfl_xor(sa, m, 64);
        se += __shfl_xor(se, m, 64);
        sg += __shfl_xor(sg, m, 64);
    }
    if (l == 0) {
        float k = fminf(fmaxf(fmaxf(sk + kb[0], 0.0f), 0.1f),   1.0f);
        float a = fminf(fmaxf(fmaxf(sa + ab[0], 0.0f), 0.001f), 0.1f);
        float e = fminf(fmaxf(fmaxf(se + eb[0], 0.0f), 0.005f), 0.1f);
        float g = fminf(fmaxf(fmaxf(sg + gb[0], 0.0f), 0.5f),   2.0f);
        out3[row] = a;
        out4[row] = k * 1000.0f;
        out5[row] = e;
        out6[row] = g;
        wsp[row]          = k;
        wsp[512 + row]    = a;
        wsp[1024 + row]   = e;
        wsp[1536 + row]   = g;
    }
}

// -------- fused: truncated-Gaussian FIR + finite diffs + physics + outputs ---
__global__ __launch_bounds__(CBLK) void pc_fused_kernel(
    const float* __restrict__ v,
    const float* __restrict__ wsp,
    const float* __restrict__ wtab,
    const int* __restrict__ use_cond,
    float* __restrict__ out0, float* __restrict__ out1,
    float* __restrict__ out2, float* __restrict__ out7,
    float* __restrict__ dvl,  float* __restrict__ dvr,
    float* __restrict__ out10)
{
    __shared__ float lds[LDSZ];
    __shared__ __align__(16) float wlds[TAPS + 7];
    __shared__ float eL[CBLK], eR[CBLK];

    const int row = blockIdx.y;
    const int i0 = blockIdx.x * CHUNK;
    const int tid = threadIdx.x;
    const float* vrow = v + (long)row * SLEN;

    // weights global -> LDS (uniform ds_read later = broadcast, conflict-free;
    // keeps ALL in-loop loads on the short-latency LDS path -- a global weight
    // load would share lgkmcnt and serialize against window ds_reads)
    for (int j = tid; j < TAPS; j += CBLK) wlds[j] = wtab[j];

    // stage window [i0-176, i0-176+2400), zero-padded, swizzled phi(x)=x+(x>>3)
    // (aligned float4 stays contiguous under phi: phi(4q+k)=phi(4q)+k)
    const int st = i0 - HALO_L;
    for (int q = tid; q < WIN / 4; q += CBLK) {
        const int g0 = st + 4 * q;
        float4 val;
        if (g0 >= 0 && g0 + 3 < SLEN) {
            val = *(const float4*)(vrow + g0);
        } else {
            val.x = (g0 >= 0     && g0     < SLEN) ? vrow[g0]     : 0.0f;
            val.y = (g0 + 1 >= 0 && g0 + 1 < SLEN) ? vrow[g0 + 1] : 0.0f;
            val.z = (g0 + 2 >= 0 && g0 + 2 < SLEN) ? vrow[g0 + 2] : 0.0f;
            val.w = (g0 + 3 >= 0 && g0 + 3 < SLEN) ? vrow[g0 + 3] : 0.0f;
        }
        const int p = 4 * q + ((4 * q) >> 3);
        lds[p] = val.x; lds[p + 1] = val.y; lds[p + 2] = val.z; lds[p + 3] = val.w;
    }
    __syncthreads();

    // block-edge v_s: wave0 -> v_s[i0-1], wave1 -> v_s[i0+2048].
    // 64-lane strided partial dot (weights via __expf; err ~1e-6 x2.5e7 amp
    // ~25 abs -- fine) + shfl butterfly.
    float edge;
    {
        const int l = tid & 63;
        const int xb = (tid < 64) ? 15 : 2064;
        float p = 0.0f;
#pragma unroll
        for (int r = 0; r < 6; ++r) {
            const int j = l + (r << 6);
            if (j < TAPS) {
                const float d = (float)(j - RAD);
                const int x = xb + j;
                p += __expf(d * d * (-1.0f / 1800.0f)) * lds[x + (x >> 3)];
            }
        }
#pragma unroll
        for (int m = 1; m < 64; m <<= 1) p += __shfl_xor(p, m, 64);
        edge = p * (float)(1.0 / 75.1988482389300059);
    }

    // FIR: thread outputs i = i0 + 16*tid + c (c=0..15); window x = 16*tid+16+j+c.
    // 8-groups are contiguous under phi: group a at lds + 9*a. Base group
    // a0 = 2*tid+2; block M (taps 16M..16M+15) uses groups a0+2M .. a0+2M+3.
    float acc[TPO];
#pragma unroll
    for (int t = 0; t < TPO; ++t) acc[t] = 0.0f;

    const float* pg = lds + 18 * tid + 18;   // group a0
    float sreg[32];
#pragma unroll
    for (int k = 0; k < 8; ++k) {
        sreg[k]      = pg[k];
        sreg[8 + k]  = pg[9 + k];
        sreg[16 + k] = pg[18 + k];
        sreg[24 + k] = pg[27 + k];
    }

#pragma unroll 2
    for (int M = 0; M < 20; ++M) {
        // wave-uniform LDS weight reads -> broadcast, no conflicts
        const float4 wA = *(const float4*)(wlds + 16 * M);
        const float4 wB = *(const float4*)(wlds + 16 * M + 4);
        const float4 wC = *(const float4*)(wlds + 16 * M + 8);
        const float4 wD = *(const float4*)(wlds + 16 * M + 12);
        const float wc[16] = {wA.x, wA.y, wA.z, wA.w, wB.x, wB.y, wB.z, wB.w,
                              wC.x, wC.y, wC.z, wC.w, wD.x, wD.y, wD.z, wD.w};
        // prefetch next 2 groups (M=19 reads up to phi-idx 2698 -- in bounds)
        float nf[16];
        const float* pn = pg + 9 * (4 + 2 * M);
#pragma unroll
        for (int k = 0; k < 8; ++k) { nf[k] = pn[k]; nf[8 + k] = pn[9 + k]; }
#pragma unroll
        for (int c = 0; c < 16; ++c) {
#pragma unroll
            for (int t = 0; t < TPO; ++t) acc[t] += wc[c] * sreg[c + t];
        }
#pragma unroll
        for (int k = 0; k < 16; ++k) sreg[k] = sreg[k + 16];
#pragma unroll
        for (int k = 0; k < 16; ++k) sreg[16 + k] = nf[k];
    }
    {   // final tap j = 320: x = 16*tid + 336 + t -> sreg[16 + t]
        const float w320 = wlds[320];
#pragma unroll
        for (int t = 0; t < TPO; ++t) acc[t] += w320 * sreg[16 + t];
    }

    eL[tid] = acc[0];
    eR[tid] = acc[15];
    __syncthreads();

    const int i8 = i0 + 16 * tid;
    if (i8 < SLEN) {   // grid covers 8192 > 8000: tail threads of the last
                       // block must do NOTHING (stores would clobber next row).
                       // Within the guard 16 | 8000 -> thread fully in-range.
        const float vprev = (tid > 0)        ? eR[tid - 1] : edge;  // wave0 edge
        const float vnext = (tid < CBLK - 1) ? eL[tid + 1] : edge;  // wave1 edge

        const float kk = wsp[row];
        const float aa = wsp[512 + row];
        const float ee = wsp[1024 + row];
        const float gg = wsp[1536 + row];
        const int uc = *use_cond;

        constexpr float DT = 1.6f / 7999.0f;
        constexpr float C1 = 1.0f / (2.0f * DT);
        constexpr float C2 = 1.0f / (DT * DT);

        const long rs = (long)row * SLEN + i8;
        const long rb = (long)row * (SLEN + 1) + i8;
        const long r0 = (long)row * 7700;

        // ---- store discipline: each array written as 4 back-to-back float4
        // stores = the thread's full 64-B line in consecutive issue slots.
        // (round-5's h-split left lines half-dirty -> partial writebacks:
        // WRITE_SIZE 166 MB vs 114 MB of payload, hbm stuck at 2 TB/s)

        // pass 1: dv_t -> out1
        float dvt[16];
#pragma unroll
        for (int c = 0; c < 16; ++c) {
            const int i = i8 + c;
            float vm = (c == 0)  ? vprev : acc[c - 1];
            float vp = (c == 15) ? vnext : acc[c + 1];
            if (i == 0) vm = 0.0f;
            if (i == SLEN - 1) vp = 0.0f;
            dvt[c] = (vp - vm) * C1;
        }
        nt_store4(out1 + rs,      dvt[0],  dvt[1],  dvt[2],  dvt[3]);
        nt_store4(out1 + rs + 4,  dvt[4],  dvt[5],  dvt[6],  dvt[7]);
        nt_store4(out1 + rs + 8,  dvt[8],  dvt[9],  dvt[10], dvt[11]);
        nt_store4(out1 + rs + 12, dvt[12], dvt[13], dvt[14], dvt[15]);

        // pass 2: dv2_t -> out2
        float dv2a[16];
#pragma unroll
        for (int c = 0; c < 16; ++c) {
            const int i = i8 + c;
            float vm = (c == 0)  ? vprev : acc[c - 1];
            float vp = (c == 15) ? vnext : acc[c + 1];
            if (i == 0) vm = 0.0f;
            if (i == SLEN - 1) vp = 0.0f;
            dv2a[c] = (vp + vm - 2.0f * acc[c]) * C2;
        }
        nt_store4(out2 + rs,      dv2a[0],  dv2a[1],  dv2a[2],  dv2a[3]);
        nt_store4(out2 + rs + 4,  dv2a[4],  dv2a[5],  dv2a[6],  dv2a[7]);
        nt_store4(out2 + rs + 8,  dv2a[8],  dv2a[9],  dv2a[10], dv2a[11]);
        nt_store4(out2 + rs + 12, dv2a[12], dv2a[13], dv2a[14], dv2a[15]);

        // pass 3: physics -> log -> out0 (reuses dvt/dv2a)
        float lg[16];
#pragma unroll
        for (int c = 0; c < 16; ++c) {
            const float vc = acc[c];
            const float dv_t = dvt[c];
            float vn = (vc == 0.0f) ? 0.001f : vc;
            float inv_v = 1.0f / vn;
            if (inv_v != inv_v) inv_v = 0.0f;
            const float term_l1 = vc * kk * dv_t * (1.0f - 2.0f * vc + aa);
            const float term_l2 = inv_v * dv_t * dv_t;
            const float term_lt = 1000.0f * term_l1 + term_l2 - dv2a[c];
            const float term_r1 = vc * (vc - gg * kk * 1000.0f * (1.0f - vc) * (vc - aa));
            const float term_rt = ee * (term_r1 + gg * dv_t);
            float dvo = term_lt - term_rt;
            if (uc) {
                if (vrow[i8 + c] <= 0.0f) dvo = 0.0f;
            }
            lg[c] = __logf(dvo * dvo + 1e-5f);
        }
        if (i8 >= 100 && i8 + 16 <= 950) {
            const long p = r0 + i8 - 100;
            nt_store4(out0 + p,      lg[0],  lg[1],  lg[2],  lg[3]);
            nt_store4(out0 + p + 4,  lg[4],  lg[5],  lg[6],  lg[7]);
            nt_store4(out0 + p + 8,  lg[8],  lg[9],  lg[10], lg[11]);
            nt_store4(out0 + p + 12, lg[12], lg[13], lg[14], lg[15]);
        } else if (i8 >= 1050 && i8 + 16 <= 7900) {
            const long p = r0 + i8 - 200;
            nt_store4(out0 + p,      lg[0],  lg[1],  lg[2],  lg[3]);
            nt_store4(out0 + p + 4,  lg[4],  lg[5],  lg[6],  lg[7]);
            nt_store4(out0 + p + 8,  lg[8],  lg[9],  lg[10], lg[11]);
            nt_store4(out0 + p + 12, lg[12], lg[13], lg[14], lg[15]);
        } else {
#pragma unroll
            for (int c = 0; c < 16; ++c) {
                const int i = i8 + c;
                if (i >= 100 && i < 950)        out0[r0 + (i - 100)] = lg[c];
                else if (i >= 1050 && i < 7900) out0[r0 + (i - 200)] = lg[c];
            }
        }

        // v_s -> dv_r[i], dv_l[i+1]
        nt_store4u(dvr + rb,      acc[0],  acc[1],  acc[2],  acc[3]);
        nt_store4u(dvr + rb + 4,  acc[4],  acc[5],  acc[6],  acc[7]);
        nt_store4u(dvr + rb + 8,  acc[8],  acc[9],  acc[10], acc[11]);
        nt_store4u(dvr + rb + 12, acc[12], acc[13], acc[14], acc[15]);
        nt_store4u(dvl + rb + 1,  acc[0],  acc[1],  acc[2],  acc[3]);
        nt_store4u(dvl + rb + 5,  acc[4],  acc[5],  acc[6],  acc[7]);
        nt_store4u(dvl + rb + 9,  acc[8],  acc[9],  acc[10], acc[11]);
        nt_store4u(dvl + rb + 13, acc[12], acc[13], acc[14], acc[15]);

        // constants 1.6 -> out7, out10
        nt_store4(out7 + rs,      1.6f, 1.6f, 1.6f, 1.6f);
        nt_store4(out7 + rs + 4,  1.6f, 1.6f, 1.6f, 1.6f);
        nt_store4(out7 + rs + 8,  1.6f, 1.6f, 1.6f, 1.6f);
        nt_store4(out7 + rs + 12, 1.6f, 1.6f, 1.6f, 1.6f);
        nt_store4(out10 + rs,      1.6f, 1.6f, 1.6f, 1.6f);
        nt_store4(out10 + rs + 4,  1.6f, 1.6f, 1.6f, 1.6f);
        nt_store4(out10 + rs + 8,  1.6f, 1.6f, 1.6f, 1.6f);
        nt_store4(out10 + rs + 12, 1.6f, 1.6f, 1.6f, 1.6f);

        if (i8 == 0)           dvl[(long)row * (SLEN + 1)] = 0.0f;
        if (i8 == SLEN - TPO)  dvr[(long)row * (SLEN + 1) + SLEN] = 0.0f;
    }
}

extern "C" void kernel_launch(void* const* d_in, const int* in_sizes, int n_in,
                              void* d_out, int out_size, void* d_ws, size_t ws_size,
                              hipStream_t stream)
{
    const float* v_out = (const float*)d_in[0];
    const float* b  = (const float*)d_in[1];
    const float* kw = (const float*)d_in[2];
    const float* kb = (const float*)d_in[3];
    const float* aw = (const float*)d_in[4];
    const float* ab = (const float*)d_in[5];
    const float* ew = (const float*)d_in[6];
    const float* eb = (const float*)d_in[7];
    const float* gw = (const float*)d_in[8];
    const float* gb = (const float*)d_in[9];
    const int* use_cond = (const int*)d_in[10];
    float* out = (float*)d_out;
    float* wsp = (float*)d_ws;   // [0,2048): k,a,eps,gamma; [2048,2369): wtab

    pc_wtab_kernel<<<1, 384, 0, stream>>>(wsp + WS_WTAB);

    pc_params_kernel<<<NBATCH, 64, 0, stream>>>(
        b, kw, kb, aw, ab, ew, eb, gw, gb,
        out + O3, out + O4, out + O5, out + O6, wsp);

    pc_fused_kernel<<<dim3((SLEN + CHUNK - 1) / CHUNK, NBATCH), CBLK, 0, stream>>>(
        v_out, wsp, wsp + WS_WTAB, use_cond,
        out + O0, out + O1, out + O2, out + O7,
        out + O8, out + O9, out + O10);
}